// Round 11
// baseline (330.056 us; speedup 1.0000x reference)
//
#include <hip/hip_runtime.h>
#include <hip/hip_bf16.h>
#include <hip/hip_fp16.h>

#define NN 20000   // nodes
#define FD 512     // features
#define NH 8       // heads
#define NE 320000  // edges
#define MP 20096   // padded rows = 157*128

typedef unsigned int u32;
typedef unsigned short u16;
typedef __bf16 bf16x8 __attribute__((ext_vector_type(8)));
typedef _Float16 f16x8 __attribute__((ext_vector_type(8)));
typedef float f32x4 __attribute__((ext_vector_type(4)));

#define AS1 __attribute__((address_space(1)))
#define AS3 __attribute__((address_space(3)))

__device__ __forceinline__ u16 f2bf(float f) {
  __hip_bfloat16 h = __float2bfloat16(f);
  union { __hip_bfloat16 b; u16 u; } c; c.b = h; return c.u;
}
__device__ __forceinline__ float bf2f(u32 u) { return __uint_as_float(u << 16); }
__device__ __forceinline__ u16 f2h(float f) {
  union { __half h; u16 u; } c; c.h = __float2half(f); return c.u;
}
__device__ __forceinline__ void gl_lds16(const void* g, void* l) {
  __builtin_amdgcn_global_load_lds((AS1 void*)const_cast<void*>(g), (AS3 void*)l, 16, 0, 0);
}
__device__ __forceinline__ void up_h4(uint2 w, float* f) {
  union { u32 u; __half2 h; } c;
  c.u = w.x; float2 t0 = __half22float2(c.h); f[0]=t0.x; f[1]=t0.y;
  c.u = w.y; float2 t1 = __half22float2(c.h); f[2]=t1.x; f[3]=t1.y;
}
__device__ __forceinline__ void up_b8(uint4 w, float* f) {
  f[0]=bf2f(w.x & 0xffffu); f[1]=bf2f(w.x >> 16);
  f[2]=bf2f(w.y & 0xffffu); f[3]=bf2f(w.y >> 16);
  f[4]=bf2f(w.z & 0xffffu); f[5]=bf2f(w.z >> 16);
  f[6]=bf2f(w.w & 0xffffu); f[7]=bf2f(w.w >> 16);
}

// ---- feat->fp16 + all weight prep + LN2-fold vectors + degree histogram ----
// Bqkvs col n (0..2047), pre-permuted so GEMM MODE6 stores are linear:
//   n<1024: group g=n>>3, j=n&7: j<4 -> Wq dim 4g+(j&3), else Wv dim 4g+(j&3)
//   n<1536: Wk col n-1024 -> Kb ; else Wsk col n-1536 -> SKIPb
// B1t = (diag(g2) W1)^T bf16 ; uw[0..512)=g2^T W1, uw[512..1024)=b2^T W1 (f32)
__global__ __launch_bounds__(256) void k_wprep(const float* __restrict__ feat,
    const float* __restrict__ Wq, const float* __restrict__ Wk,
    const float* __restrict__ Wv, const float* __restrict__ Wsk,
    const float* __restrict__ Wn, const float* __restrict__ W1,
    const float* __restrict__ W2, const float* __restrict__ Wg,
    const float* __restrict__ l2g, const float* __restrict__ l2b,
    const int* __restrict__ e_dst,
    u16* __restrict__ Af, u16* __restrict__ Bqkvs, u16* __restrict__ Bnt,
    u16* __restrict__ B1t, u16* __restrict__ B2t,
    float* __restrict__ gA, float* __restrict__ gB,
    float* __restrict__ uw, int* __restrict__ deg)
{
  int idx = blockIdx.x * 256 + threadIdx.x;
  if (idx < MP * FD / 4) {
    size_t i = (size_t)idx * 4;
    float4 v = make_float4(0.f, 0.f, 0.f, 0.f);
    if (i < (size_t)NN * FD) v = *(const float4*)(feat + i);
    *(ushort4*)(Af + i) = make_ushort4(f2h(v.x), f2h(v.y), f2h(v.z), f2h(v.w));
    return;
  }
  idx -= MP * FD / 4;
  if (idx < 2048 * 512) {
    int n = idx >> 9, k = idx & 511;
    float v;
    if (n < 1024) {
      int j = n & 7, dim = (n >> 3) * 4 + (j & 3);
      v = (j < 4) ? Wq[k * 512 + dim] : Wv[k * 512 + dim];
    } else if (n < 1536) v = Wk[k * 512 + (n - 1024)];
    else                 v = Wsk[k * 512 + (n - 1536)];
    Bqkvs[idx] = f2h(v);
    return;
  }
  idx -= 2048 * 512;
  if (idx < 512 * 512) { int n = idx >> 9, k = idx & 511; Bnt[idx] = f2bf(Wn[k * 512 + n]); return; }
  idx -= 512 * 512;
  if (idx < 512 * 512) { int n = idx >> 9, k = idx & 511;
    B1t[idx] = f2bf(l2g[k] * W1[k * 512 + n]); return; }
  idx -= 512 * 512;
  if (idx < 512 * 512) { int n = idx >> 9, k = idx & 511; B2t[idx] = f2bf(W2[k * 512 + n]); return; }
  idx -= 512 * 512;
  if (idx < 512) {
    gA[idx] = Wg[idx] + Wg[2 * 512 + idx];
    gB[idx] = Wg[512 + idx] - Wg[2 * 512 + idx];
    return;
  }
  idx -= 512;
  if (idx < 1024) {
    int j = idx & 511;
    const float* vec = (idx < 512) ? l2g : l2b;
    float acc = 0.f;
    for (int c = 0; c < 512; c++) acc += vec[c] * W1[c * 512 + j];
    uw[idx] = acc;
    return;
  }
  idx -= 1024;
  if (idx < NE) atomicAdd(&deg[e_dst[idx]], 1);
}

// ---- GEMM: A[M,512] x Bt[NCOLS,512] (both u16-encoded, FP16 or bf16) ----
// 128x128 tile, BK=32 double-buffer at 32 KB LDS, 4 blocks/CU, XCD=row%8.
// MODE: 2=bf16->Cb,
//       6=QKVS split store: col<1024 -> Cb=QV (interleaved q|v fp16, linear);
//                           col<1536 -> Cb2=Kb fp16; else Cb3=SKIPb bf16
//       7=h+ffn: Cf[o] = bf2f(Cb2[o]) + v   (writes d_out once)
//       8=LN2-fold+relu: Cb[o] = bf16(relu(rs2[row]*v - rm2[row]*u[col] + w[col]))
//         with Cf=scal=[rs2|rm2], Cb2 reinterpreted as uw=[u|w]
template<int NCOLS, int MODE, int FP16>
__global__ __launch_bounds__(256, 4) void k_gemm(
    const u16* __restrict__ A, const u16* __restrict__ B,
    float* __restrict__ Cf, u16* __restrict__ Cb, u16* __restrict__ Cb2,
    u16* __restrict__ Cb3, int Mreal)
{
  const long brow = (long)blockIdx.x * 128;
  if (brow >= MP) return;
  __shared__ u16 sA[2][128 * 32];
  __shared__ u16 sB[2][128 * 32];
  const int tid = threadIdx.x, lane = tid & 63, w = tid >> 6;
  const int wr = w >> 1, wc = w & 1;
  const long bcol = (long)blockIdx.y * 128;
  const int srl = tid >> 2, scl = (tid & 3) * 8;

  auto stage = [&](int b, int kt) {
#pragma unroll
    for (int s = 0; s < 2; s++) {
      gl_lds16(A + (brow + s * 64 + srl) * FD + kt + scl, &sA[b][s * 2048 + w * 512]);
      gl_lds16(B + (bcol + s * 64 + srl) * FD + kt + scl, &sB[b][s * 2048 + w * 512]);
    }
  };

  f32x4 acc[4][4] = {};
  stage(0, 0);
  __syncthreads();
  int cur = 0;
  const int ro = (lane >> 4) * 8;
  for (int kt = 0; kt < FD; kt += 32) {
    if (kt + 32 < FD) stage(cur ^ 1, kt + 32);
#pragma unroll
    for (int m = 0; m < 4; m++) {
      const u16* pa = &sA[cur][(wr * 64 + m * 16 + (lane & 15)) * 32 + ro];
#pragma unroll
      for (int n = 0; n < 4; n++) {
        const u16* pb = &sB[cur][(wc * 64 + n * 16 + (lane & 15)) * 32 + ro];
        if constexpr (FP16)
          acc[m][n] = __builtin_amdgcn_mfma_f32_16x16x32_f16(
              *(const f16x8*)pa, *(const f16x8*)pb, acc[m][n], 0, 0, 0);
        else
          acc[m][n] = __builtin_amdgcn_mfma_f32_16x16x32_bf16(
              *(const bf16x8*)pa, *(const bf16x8*)pb, acc[m][n], 0, 0, 0);
      }
    }
    __syncthreads();
    cur ^= 1;
  }
  const float* uwp = (const float*)Cb2;  // MODE 8 only
#pragma unroll
  for (int m = 0; m < 4; m++) {
    long row0 = brow + wr * 64 + m * 16 + (lane >> 4) * 4;
#pragma unroll
    for (int n = 0; n < 4; n++) {
      long col = bcol + wc * 64 + n * 16 + (lane & 15);
#pragma unroll
      for (int j = 0; j < 4; j++) {
        long row = row0 + j;
        if (row < Mreal) {
          float v = acc[m][n][j];
          if constexpr (MODE == 2) Cb[row * NCOLS + col] = f2bf(v);
          else if constexpr (MODE == 6) {
            if (col < 1024)      Cb[row * 1024 + col] = f2h(v);
            else if (col < 1536) Cb2[row * 512 + (col - 1024)] = f2h(v);
            else                 Cb3[row * 512 + (col - 1536)] = f2bf(v);
          } else if constexpr (MODE == 7) {
            long o = row * NCOLS + col;
            Cf[o] = bf2f((u32)Cb2[o]) + v;
          } else {  // MODE 8
            float val = Cf[row] * v - Cf[NN + row] * uwp[col] + uwp[512 + col];
            Cb[row * NCOLS + col] = f2bf(fmaxf(val, 0.f));
          }
        }
      }
    }
  }
}

// ---- single-pass scan: thread t serially scans 20 elems, 2 block barriers ----
__global__ __launch_bounds__(1024) void k_scan(const int* __restrict__ deg, int* __restrict__ offa)
{
  __shared__ int wsum[16];
  const int tid = threadIdx.x, lane = tid & 63, wid = tid >> 6;
  const int base = tid * 20;
  int loc[20];
  int s = 0;
#pragma unroll
  for (int j = 0; j < 20; j++) {
    int i = base + j;
    int v = (i < NN) ? deg[i] : 0;
    s += v; loc[j] = s;
  }
  int incl = s;
#pragma unroll
  for (int d = 1; d < 64; d <<= 1) { int t = __shfl_up(incl, d); if (lane >= d) incl += t; }
  if (lane == 63) wsum[wid] = incl;
  __syncthreads();
  if (tid < 16) {
    int ws = wsum[tid];
#pragma unroll
    for (int d = 1; d < 16; d <<= 1) { int t = __shfl_up(ws, d, 16); if (tid >= d) ws += t; }
    wsum[tid] = ws;
  }
  __syncthreads();
  int prev = incl - s + (wid ? wsum[wid - 1] : 0);
  if (tid == 0) offa[0] = 0;
#pragma unroll
  for (int j = 0; j < 20; j++) {
    int i = base + j;
    if (i < NN) offa[i + 1] = prev + loc[j];
  }
}

__global__ __launch_bounds__(256) void k_scatter(const int* __restrict__ src, const int* __restrict__ dst,
    const int* __restrict__ offa, int* __restrict__ cnt, int* __restrict__ esrcs)
{
  int e = blockIdx.x * 256 + threadIdx.x;
  if (e >= NE) return;
  int d = dst[e];
  int p = offa[d] + atomicAdd(&cnt[d], 1);
  esrcs[p] = src[e];
}

// ---- fused edge pass: 2 waves per dst node, interleaved QV (one uint4/lane/edge) ----
__global__ __launch_bounds__(256) void k_edge(const int* __restrict__ offa,
    const int* __restrict__ esrcs, const u16* __restrict__ QV,
    const u16* __restrict__ Kb, u16* __restrict__ aggb)
{
  int wid = blockIdx.x * 4 + (threadIdx.x >> 6);
  int nd = wid >> 1, half = wid & 1;
  int lane = threadIdx.x & 63;
  if (nd >= MP) return;
  const int g = half * 64 + lane;          // 4-dim group index, dims [4g,4g+4)
  u16* op = aggb + (size_t)nd * FD + g * 4;
  if (nd >= NN) { *(ushort4*)op = make_ushort4(0, 0, 0, 0); return; }
  uint2 kw = *(const uint2*)(Kb + (size_t)nd * 512 + g * 4);
  float kx[4]; up_h4(kw, kx);
  int b0 = offa[nd], b1 = offa[nd + 1];
  float den = 0.f, a0 = 0.f, a1 = 0.f, a2 = 0.f, a3 = 0.f;
  for (int p = b0; p < b1; p += 8) {
    int ss[8]; uint4 qv[8];
#pragma unroll
    for (int u = 0; u < 8; u++) { int ix = p + u; ss[u] = esrcs[ix < b1 ? ix : b1 - 1]; }
#pragma unroll
    for (int u = 0; u < 8; u++)
      qv[u] = *(const uint4*)(QV + (size_t)ss[u] * 1024 + g * 8);
#pragma unroll
    for (int u = 0; u < 8; u++) {
      float qx[4]; up_h4(make_uint2(qv[u].x, qv[u].y), qx);
      float d = qx[0]*kx[0] + qx[1]*kx[1] + qx[2]*kx[2] + qx[3]*kx[3];
      d += __shfl_xor(d, 1); d += __shfl_xor(d, 2);
      d += __shfl_xor(d, 4); d += __shfl_xor(d, 8);
      float ex = __expf(fminf(fmaxf(d, -5.f), 5.f) * 8.f - 40.f);
      ex = (p + u < b1) ? ex : 0.f;
      den += ex;
      float vx[4]; up_h4(make_uint2(qv[u].z, qv[u].w), vx);
      a0 += ex * vx[0]; a1 += ex * vx[1]; a2 += ex * vx[2]; a3 += ex * vx[3];
    }
  }
  float rd = 1.f / den;
  *(ushort4*)op = make_ushort4(f2bf(a0*rd), f2bf(a1*rd), f2bf(a2*rd), f2bf(a3*rd));
}

// ---- gate GEMV + gated residual + LN1 (-> h bf16) + LN2 row stats only ----
// one wave per row: 64 lanes x 8 elems, shfl-only reductions, no barriers.
__global__ __launch_bounds__(256) void k_gate_ln(const u16* __restrict__ rstb,
    const u16* __restrict__ skpb, const float* __restrict__ gA, const float* __restrict__ gB,
    const float* __restrict__ g1, const float* __restrict__ b1,
    u16* __restrict__ hb, float* __restrict__ scal)   // scal=[rs2(NN) | rs2*m2(NN)]
{
  int nd = blockIdx.x * 4 + (threadIdx.x >> 6);
  int lane = threadIdx.x & 63;
  if (nd >= NN) return;
  const size_t base = (size_t)nd * FD + lane * 8;
  float r[8], s[8], a[8], b[8];
  up_b8(*(const uint4*)(rstb + base), r);
  up_b8(*(const uint4*)(skpb + base), s);
  *(float4*)&a[0] = *(const float4*)(gA + lane * 8);
  *(float4*)&a[4] = *(const float4*)(gA + lane * 8 + 4);
  *(float4*)&b[0] = *(const float4*)(gB + lane * 8);
  *(float4*)&b[4] = *(const float4*)(gB + lane * 8 + 4);
  float gd = 0.f;
#pragma unroll
  for (int i = 0; i < 8; i++) gd += r[i] * a[i] + s[i] * b[i];
#pragma unroll
  for (int d = 1; d < 64; d <<= 1) gd += __shfl_xor(gd, d);
  float g = 1.f / (1.f + __expf(-gd));
  float x[8], sx = 0.f, sxx = 0.f;
#pragma unroll
  for (int i = 0; i < 8; i++) {
    x[i] = g * r[i] + (1.f - g) * s[i];
    sx += x[i]; sxx += x[i] * x[i];
  }
#pragma unroll
  for (int d = 1; d < 64; d <<= 1) { sx += __shfl_xor(sx, d); sxx += __shfl_xor(sxx, d); }
  float m1 = sx * (1.f / FD);
  float v1 = sxx * (1.f / FD) - m1 * m1;
  float rs = rsqrtf(v1 + 1e-5f);
  float G1[8], Bb1[8];
  *(float4*)&G1[0] = *(const float4*)(g1 + lane * 8);
  *(float4*)&G1[4] = *(const float4*)(g1 + lane * 8 + 4);
  *(float4*)&Bb1[0] = *(const float4*)(b1 + lane * 8);
  *(float4*)&Bb1[4] = *(const float4*)(b1 + lane * 8 + 4);
  float h[8], sh = 0.f, shh = 0.f;
  u16 ho[8];
#pragma unroll
  for (int i = 0; i < 8; i++) {
    h[i] = (x[i] - m1) * rs * G1[i] + Bb1[i];
    sh += h[i]; shh += h[i] * h[i];
    ho[i] = f2bf(h[i]);
  }
  uint4 st;
  st.x = (u32)ho[0] | ((u32)ho[1] << 16);
  st.y = (u32)ho[2] | ((u32)ho[3] << 16);
  st.z = (u32)ho[4] | ((u32)ho[5] << 16);
  st.w = (u32)ho[6] | ((u32)ho[7] << 16);
  *(uint4*)(hb + base) = st;
#pragma unroll
  for (int d = 1; d < 64; d <<= 1) { sh += __shfl_xor(sh, d); shh += __shfl_xor(shh, d); }
  if (lane == 0) {
    float m2 = sh * (1.f / FD);
    float v2 = shh * (1.f / FD) - m2 * m2;
    float rs2 = rsqrtf(v2 + 1e-5f);
    scal[nd] = rs2;
    scal[NN + nd] = rs2 * m2;
  }
}

extern "C" void kernel_launch(void* const* d_in, const int* in_sizes, int n_in,
                              void* d_out, int out_size, void* d_ws, size_t ws_size,
                              hipStream_t stream)
{
  const float* feat = (const float*)d_in[0];
  const int* e_src = (const int*)d_in[1];
  const int* e_dst = (const int*)d_in[2];
  const float* Wq  = (const float*)d_in[3];
  const float* Wk  = (const float*)d_in[4];
  const float* Wv  = (const float*)d_in[5];
  const float* Wn  = (const float*)d_in[6];
  const float* Wsk = (const float*)d_in[7];
  const float* Wg  = (const float*)d_in[8];
  const float* l1g = (const float*)d_in[9];
  const float* l1b = (const float*)d_in[10];
  const float* l2g = (const float*)d_in[11];
  const float* l2b = (const float*)d_in[12];
  const float* W1  = (const float*)d_in[13];
  const float* W2  = (const float*)d_in[14];

  char* ws = (char*)d_ws;
  size_t o = 0;
  auto al = [&](size_t b) { char* r = ws + o; o = (o + b + 255) & ~(size_t)255; return r; };

  u16* Af    = (u16*)al((size_t)MP * FD * 2);      // feat fp16
  u16* Bqkvs = (u16*)al((size_t)2048 * FD * 2);    // permuted [q|v interleave, K, SKIP]^T fp16
  u16* Bnt   = (u16*)al((size_t)FD * FD * 2);
  u16* B1t   = (u16*)al((size_t)FD * FD * 2);      // (diag(g2) W1)^T bf16
  u16* B2t   = (u16*)al((size_t)FD * FD * 2);
  float* gA  = (float*)al(FD * 4);
  float* gB  = (float*)al(FD * 4);
  float* uw  = (float*)al(1024 * 4);               // [g2^T W1 | b2^T W1]
  u16* QV    = (u16*)al((size_t)MP * 1024 * 2);    // interleaved [q|v] fp16 per node
  u16* Kb    = (u16*)al((size_t)MP * FD * 2);      // k fp16
  u16* SKIPb = (u16*)al((size_t)MP * FD * 2);      // bf16
  u16* aggb  = (u16*)al((size_t)MP * FD * 2);      // bf16
  u16* hb    = (u16*)al((size_t)MP * FD * 2);      // bf16 (h)
  float* scal= (float*)al((size_t)2 * NN * 4);     // [rs2 | rs2*m2]
  int* deg   = (int*)al((size_t)2 * NN * 4);
  int* cnt   = deg + NN;
  int* offa  = (int*)al((size_t)(NN + 1) * 4);
  int* esrcs = (int*)al((size_t)NE * 4);
  if (o > ws_size) return;  // ~150 MB needed
  // aliases into dead regions
  u16* rstb = Kb;    // Kb dead after k_edge
  u16* midb = Af;    // Af dead after QKVS GEMM
  float* out = (float*)d_out;

  hipMemsetAsync(deg, 0, (size_t)2 * NN * 4, stream);

  {
    int total = MP * FD / 4 + 2048 * 512 + 3 * 512 * 512 + 512 + 1024 + NE;
    k_wprep<<<dim3((total + 255) / 256), 256, 0, stream>>>(feat, Wq, Wk, Wv, Wsk, Wn, W1, W2, Wg,
        l2g, l2b, e_dst, Af, Bqkvs, Bnt, B1t, B2t, gA, gB, uw, deg);
  }

  // one fp16 GEMM for Q,K,V,SKIP  [MP x 2048 x 512], 128x128 tile, XCD=row%8
  k_gemm<2048, 6, 1><<<dim3(160, 16), 256, 0, stream>>>(Af, Bqkvs, nullptr, QV, Kb, SKIPb, MP);

  k_scan<<<dim3(1), 1024, 0, stream>>>(deg, offa);
  k_scatter<<<dim3((NE + 255) / 256), 256, 0, stream>>>(e_src, e_dst, offa, cnt, esrcs);
  k_edge<<<dim3(MP / 2), 256, 0, stream>>>(offa, esrcs, QV, Kb, aggb);

  k_gemm<512, 2, 0><<<dim3(160, 4), 256, 0, stream>>>(aggb, Bnt, nullptr, rstb, nullptr, nullptr, MP);
  k_gate_ln<<<dim3((NN + 3) / 4), 256, 0, stream>>>(rstb, SKIPb, gA, gB, l1g, l1b, hb, scal);
  k_gemm<512, 8, 0><<<dim3(160, 4), 256, 0, stream>>>(hb, B1t, scal, midb, (u16*)uw, nullptr, NN);
  k_gemm<512, 7, 0><<<dim3(160, 4), 256, 0, stream>>>(midb, B2t, out, nullptr, hb, nullptr, NN);
}

// Round 12
// 319.066 us; speedup vs baseline: 1.0344x; 1.0344x over previous
//
#include <hip/hip_runtime.h>
#include <hip/hip_bf16.h>
#include <hip/hip_fp16.h>

#define NN 20000   // nodes
#define FD 512     // features
#define NH 8       // heads
#define NE 320000  // edges
#define MP 20096   // padded rows = 157*128

typedef unsigned int u32;
typedef unsigned short u16;
typedef __bf16 bf16x8 __attribute__((ext_vector_type(8)));
typedef _Float16 f16x8 __attribute__((ext_vector_type(8)));
typedef float f32x4 __attribute__((ext_vector_type(4)));

#define AS1 __attribute__((address_space(1)))
#define AS3 __attribute__((address_space(3)))

__device__ __forceinline__ u16 f2bf(float f) {
  __hip_bfloat16 h = __float2bfloat16(f);
  union { __hip_bfloat16 b; u16 u; } c; c.b = h; return c.u;
}
__device__ __forceinline__ float bf2f(u32 u) { return __uint_as_float(u << 16); }
__device__ __forceinline__ u16 f2h(float f) {
  union { __half h; u16 u; } c; c.h = __float2half(f); return c.u;
}
__device__ __forceinline__ void gl_lds16(const void* g, void* l) {
  __builtin_amdgcn_global_load_lds((AS1 void*)const_cast<void*>(g), (AS3 void*)l, 16, 0, 0);
}
__device__ __forceinline__ void up_h4(uint2 w, float* f) {
  union { u32 u; __half2 h; } c;
  c.u = w.x; float2 t0 = __half22float2(c.h); f[0]=t0.x; f[1]=t0.y;
  c.u = w.y; float2 t1 = __half22float2(c.h); f[2]=t1.x; f[3]=t1.y;
}
__device__ __forceinline__ void up_b8(uint4 w, float* f) {
  f[0]=bf2f(w.x & 0xffffu); f[1]=bf2f(w.x >> 16);
  f[2]=bf2f(w.y & 0xffffu); f[3]=bf2f(w.y >> 16);
  f[4]=bf2f(w.z & 0xffffu); f[5]=bf2f(w.z >> 16);
  f[6]=bf2f(w.w & 0xffffu); f[7]=bf2f(w.w >> 16);
}

// ---- feat->fp16 + all weight prep + LN2-fold vectors + degree histogram ----
// Bqkvs col n (0..2047), pre-permuted so GEMM MODE6 stores are linear:
//   n<1024: group g=n>>3, j=n&7: j<4 -> Wq dim 4g+(j&3), else Wv dim 4g+(j&3)
//   n<1536: Wk col n-1024 -> Kb ; else Wsk col n-1536 -> SKIPb
// B1t = (diag(g2) W1)^T bf16 ; uw[0..512)=g2^T W1, uw[512..1024)=b2^T W1 (f32,
// computed as 8 atomic partials per output -- r11 lesson: a serial 512-iter
// per-thread loop here put ~10us on wprep's critical path)
__global__ __launch_bounds__(256) void k_wprep(const float* __restrict__ feat,
    const float* __restrict__ Wq, const float* __restrict__ Wk,
    const float* __restrict__ Wv, const float* __restrict__ Wsk,
    const float* __restrict__ Wn, const float* __restrict__ W1,
    const float* __restrict__ W2, const float* __restrict__ Wg,
    const float* __restrict__ l2g, const float* __restrict__ l2b,
    const int* __restrict__ e_dst,
    u16* __restrict__ Af, u16* __restrict__ Bqkvs, u16* __restrict__ Bnt,
    u16* __restrict__ B1t, u16* __restrict__ B2t,
    float* __restrict__ gA, float* __restrict__ gB,
    float* __restrict__ uw, int* __restrict__ deg)
{
  int idx = blockIdx.x * 256 + threadIdx.x;
  if (idx < MP * FD / 4) {
    size_t i = (size_t)idx * 4;
    float4 v = make_float4(0.f, 0.f, 0.f, 0.f);
    if (i < (size_t)NN * FD) v = *(const float4*)(feat + i);
    *(ushort4*)(Af + i) = make_ushort4(f2h(v.x), f2h(v.y), f2h(v.z), f2h(v.w));
    return;
  }
  idx -= MP * FD / 4;
  if (idx < 2048 * 512) {
    int n = idx >> 9, k = idx & 511;
    float v;
    if (n < 1024) {
      int j = n & 7, dim = (n >> 3) * 4 + (j & 3);
      v = (j < 4) ? Wq[k * 512 + dim] : Wv[k * 512 + dim];
    } else if (n < 1536) v = Wk[k * 512 + (n - 1024)];
    else                 v = Wsk[k * 512 + (n - 1536)];
    Bqkvs[idx] = f2h(v);
    return;
  }
  idx -= 2048 * 512;
  if (idx < 512 * 512) { int n = idx >> 9, k = idx & 511; Bnt[idx] = f2bf(Wn[k * 512 + n]); return; }
  idx -= 512 * 512;
  if (idx < 512 * 512) { int n = idx >> 9, k = idx & 511;
    B1t[idx] = f2bf(l2g[k] * W1[k * 512 + n]); return; }
  idx -= 512 * 512;
  if (idx < 512 * 512) { int n = idx >> 9, k = idx & 511; B2t[idx] = f2bf(W2[k * 512 + n]); return; }
  idx -= 512 * 512;
  if (idx < 512) {
    gA[idx] = Wg[idx] + Wg[2 * 512 + idx];
    gB[idx] = Wg[512 + idx] - Wg[2 * 512 + idx];
    return;
  }
  idx -= 512;
  if (idx < 8192) {                  // uw: thread (p,j) sums 64 c's, coalesced in j
    int j = idx & 1023, p = idx >> 10;
    int jj = j & 511;
    const float* vec = (j < 512) ? l2g : l2b;
    float acc = 0.f;
    int c0 = p * 64;
#pragma unroll 8
    for (int c = c0; c < c0 + 64; c++) acc += vec[c] * W1[c * 512 + jj];
    atomicAdd(&uw[j], acc);
    return;
  }
  idx -= 8192;
  if (idx < NE) atomicAdd(&deg[e_dst[idx]], 1);
}

// ---- GEMM: A[M,512] x Bt[NCOLS,512] (both u16-encoded, FP16 or bf16) ----
// 128x128 tile, BK=32 double-buffer at 32 KB LDS, 4 blocks/CU, XCD=row%8.
// MODE: 2=bf16->Cb,
//       6=QKVS split store: col<1024 -> Cb=QV (interleaved q|v fp16, linear);
//                           col<1536 -> Cb2=Kb fp16; else Cb3=SKIPb bf16
//       7=h+ffn: Cf[o] = bf2f(Cb2[o]) + v   (writes d_out once)
//       8=LN2-fold+relu: Cb[o] = bf16(relu(rs2[row]*v - rm2[row]*u[col] + w[col]))
//         with Cf=scal=[rs2|rm2], Cb2 reinterpreted as uw=[u|w]
template<int NCOLS, int MODE, int FP16>
__global__ __launch_bounds__(256, 4) void k_gemm(
    const u16* __restrict__ A, const u16* __restrict__ B,
    float* __restrict__ Cf, u16* __restrict__ Cb, u16* __restrict__ Cb2,
    u16* __restrict__ Cb3, int Mreal)
{
  const long brow = (long)blockIdx.x * 128;
  if (brow >= MP) return;
  __shared__ u16 sA[2][128 * 32];
  __shared__ u16 sB[2][128 * 32];
  const int tid = threadIdx.x, lane = tid & 63, w = tid >> 6;
  const int wr = w >> 1, wc = w & 1;
  const long bcol = (long)blockIdx.y * 128;
  const int srl = tid >> 2, scl = (tid & 3) * 8;

  auto stage = [&](int b, int kt) {
#pragma unroll
    for (int s = 0; s < 2; s++) {
      gl_lds16(A + (brow + s * 64 + srl) * FD + kt + scl, &sA[b][s * 2048 + w * 512]);
      gl_lds16(B + (bcol + s * 64 + srl) * FD + kt + scl, &sB[b][s * 2048 + w * 512]);
    }
  };

  f32x4 acc[4][4] = {};
  stage(0, 0);
  __syncthreads();
  int cur = 0;
  const int ro = (lane >> 4) * 8;
  for (int kt = 0; kt < FD; kt += 32) {
    if (kt + 32 < FD) stage(cur ^ 1, kt + 32);
#pragma unroll
    for (int m = 0; m < 4; m++) {
      const u16* pa = &sA[cur][(wr * 64 + m * 16 + (lane & 15)) * 32 + ro];
#pragma unroll
      for (int n = 0; n < 4; n++) {
        const u16* pb = &sB[cur][(wc * 64 + n * 16 + (lane & 15)) * 32 + ro];
        if constexpr (FP16)
          acc[m][n] = __builtin_amdgcn_mfma_f32_16x16x32_f16(
              *(const f16x8*)pa, *(const f16x8*)pb, acc[m][n], 0, 0, 0);
        else
          acc[m][n] = __builtin_amdgcn_mfma_f32_16x16x32_bf16(
              *(const bf16x8*)pa, *(const bf16x8*)pb, acc[m][n], 0, 0, 0);
      }
    }
    __syncthreads();
    cur ^= 1;
  }
  const float* uwp = (const float*)Cb2;  // MODE 8 only
#pragma unroll
  for (int m = 0; m < 4; m++) {
    long row0 = brow + wr * 64 + m * 16 + (lane >> 4) * 4;
#pragma unroll
    for (int n = 0; n < 4; n++) {
      long col = bcol + wc * 64 + n * 16 + (lane & 15);
#pragma unroll
      for (int j = 0; j < 4; j++) {
        long row = row0 + j;
        if (row < Mreal) {
          float v = acc[m][n][j];
          if constexpr (MODE == 2) Cb[row * NCOLS + col] = f2bf(v);
          else if constexpr (MODE == 6) {
            if (col < 1024)      Cb[row * 1024 + col] = f2h(v);
            else if (col < 1536) Cb2[row * 512 + (col - 1024)] = f2h(v);
            else                 Cb3[row * 512 + (col - 1536)] = f2bf(v);
          } else if constexpr (MODE == 7) {
            long o = row * NCOLS + col;
            Cf[o] = bf2f((u32)Cb2[o]) + v;
          } else {  // MODE 8
            float val = Cf[row] * v - Cf[NN + row] * uwp[col] + uwp[512 + col];
            Cb[row * NCOLS + col] = f2bf(fmaxf(val, 0.f));
          }
        }
      }
    }
  }
}

// ---- single-pass scan: thread t serially scans 20 elems, 2 block barriers ----
__global__ __launch_bounds__(1024) void k_scan(const int* __restrict__ deg, int* __restrict__ offa)
{
  __shared__ int wsum[16];
  const int tid = threadIdx.x, lane = tid & 63, wid = tid >> 6;
  const int base = tid * 20;
  int loc[20];
  int s = 0;
#pragma unroll
  for (int j = 0; j < 20; j++) {
    int i = base + j;
    int v = (i < NN) ? deg[i] : 0;
    s += v; loc[j] = s;
  }
  int incl = s;
#pragma unroll
  for (int d = 1; d < 64; d <<= 1) { int t = __shfl_up(incl, d); if (lane >= d) incl += t; }
  if (lane == 63) wsum[wid] = incl;
  __syncthreads();
  if (tid < 16) {
    int ws = wsum[tid];
#pragma unroll
    for (int d = 1; d < 16; d <<= 1) { int t = __shfl_up(ws, d, 16); if (tid >= d) ws += t; }
    wsum[tid] = ws;
  }
  __syncthreads();
  int prev = incl - s + (wid ? wsum[wid - 1] : 0);
  if (tid == 0) offa[0] = 0;
#pragma unroll
  for (int j = 0; j < 20; j++) {
    int i = base + j;
    if (i < NN) offa[i + 1] = prev + loc[j];
  }
}

__global__ __launch_bounds__(256) void k_scatter(const int* __restrict__ src, const int* __restrict__ dst,
    const int* __restrict__ offa, int* __restrict__ cnt, int* __restrict__ esrcs)
{
  int e = blockIdx.x * 256 + threadIdx.x;
  if (e >= NE) return;
  int d = dst[e];
  int p = offa[d] + atomicAdd(&cnt[d], 1);
  esrcs[p] = src[e];
}

// ---- fused edge pass: 2 waves per dst node, interleaved QV (one uint4/lane/edge) ----
__global__ __launch_bounds__(256) void k_edge(const int* __restrict__ offa,
    const int* __restrict__ esrcs, const u16* __restrict__ QV,
    const u16* __restrict__ Kb, u16* __restrict__ aggb)
{
  int wid = blockIdx.x * 4 + (threadIdx.x >> 6);
  int nd = wid >> 1, half = wid & 1;
  int lane = threadIdx.x & 63;
  if (nd >= MP) return;
  const int g = half * 64 + lane;          // 4-dim group index, dims [4g,4g+4)
  u16* op = aggb + (size_t)nd * FD + g * 4;
  if (nd >= NN) { *(ushort4*)op = make_ushort4(0, 0, 0, 0); return; }
  uint2 kw = *(const uint2*)(Kb + (size_t)nd * 512 + g * 4);
  float kx[4]; up_h4(kw, kx);
  int b0 = offa[nd], b1 = offa[nd + 1];
  float den = 0.f, a0 = 0.f, a1 = 0.f, a2 = 0.f, a3 = 0.f;
  for (int p = b0; p < b1; p += 8) {
    int ss[8]; uint4 qv[8];
#pragma unroll
    for (int u = 0; u < 8; u++) { int ix = p + u; ss[u] = esrcs[ix < b1 ? ix : b1 - 1]; }
#pragma unroll
    for (int u = 0; u < 8; u++)
      qv[u] = *(const uint4*)(QV + (size_t)ss[u] * 1024 + g * 8);
#pragma unroll
    for (int u = 0; u < 8; u++) {
      float qx[4]; up_h4(make_uint2(qv[u].x, qv[u].y), qx);
      float d = qx[0]*kx[0] + qx[1]*kx[1] + qx[2]*kx[2] + qx[3]*kx[3];
      d += __shfl_xor(d, 1); d += __shfl_xor(d, 2);
      d += __shfl_xor(d, 4); d += __shfl_xor(d, 8);
      float ex = __expf(fminf(fmaxf(d, -5.f), 5.f) * 8.f - 40.f);
      ex = (p + u < b1) ? ex : 0.f;
      den += ex;
      float vx[4]; up_h4(make_uint2(qv[u].z, qv[u].w), vx);
      a0 += ex * vx[0]; a1 += ex * vx[1]; a2 += ex * vx[2]; a3 += ex * vx[3];
    }
  }
  float rd = 1.f / den;
  *(ushort4*)op = make_ushort4(f2bf(a0*rd), f2bf(a1*rd), f2bf(a2*rd), f2bf(a3*rd));
}

// ---- gate GEMV + gated residual + LN1 (-> h bf16) + LN2 row stats only ----
// one wave per row: 64 lanes x 8 elems, shfl-only reductions, no barriers.
__global__ __launch_bounds__(256) void k_gate_ln(const u16* __restrict__ rstb,
    const u16* __restrict__ skpb, const float* __restrict__ gA, const float* __restrict__ gB,
    const float* __restrict__ g1, const float* __restrict__ b1,
    u16* __restrict__ hb, float* __restrict__ scal)   // scal=[rs2(NN) | rs2*m2(NN)]
{
  int nd = blockIdx.x * 4 + (threadIdx.x >> 6);
  int lane = threadIdx.x & 63;
  if (nd >= NN) return;
  const size_t base = (size_t)nd * FD + lane * 8;
  float r[8], s[8], a[8], b[8];
  up_b8(*(const uint4*)(rstb + base), r);
  up_b8(*(const uint4*)(skpb + base), s);
  *(float4*)&a[0] = *(const float4*)(gA + lane * 8);
  *(float4*)&a[4] = *(const float4*)(gA + lane * 8 + 4);
  *(float4*)&b[0] = *(const float4*)(gB + lane * 8);
  *(float4*)&b[4] = *(const float4*)(gB + lane * 8 + 4);
  float gd = 0.f;
#pragma unroll
  for (int i = 0; i < 8; i++) gd += r[i] * a[i] + s[i] * b[i];
#pragma unroll
  for (int d = 1; d < 64; d <<= 1) gd += __shfl_xor(gd, d);
  float g = 1.f / (1.f + __expf(-gd));
  float x[8], sx = 0.f, sxx = 0.f;
#pragma unroll
  for (int i = 0; i < 8; i++) {
    x[i] = g * r[i] + (1.f - g) * s[i];
    sx += x[i]; sxx += x[i] * x[i];
  }
#pragma unroll
  for (int d = 1; d < 64; d <<= 1) { sx += __shfl_xor(sx, d); sxx += __shfl_xor(sxx, d); }
  float m1 = sx * (1.f / FD);
  float v1 = sxx * (1.f / FD) - m1 * m1;
  float rs = rsqrtf(v1 + 1e-5f);
  float G1[8], Bb1[8];
  *(float4*)&G1[0] = *(const float4*)(g1 + lane * 8);
  *(float4*)&G1[4] = *(const float4*)(g1 + lane * 8 + 4);
  *(float4*)&Bb1[0] = *(const float4*)(b1 + lane * 8);
  *(float4*)&Bb1[4] = *(const float4*)(b1 + lane * 8 + 4);
  float h[8], sh = 0.f, shh = 0.f;
  u16 ho[8];
#pragma unroll
  for (int i = 0; i < 8; i++) {
    h[i] = (x[i] - m1) * rs * G1[i] + Bb1[i];
    sh += h[i]; shh += h[i] * h[i];
    ho[i] = f2bf(h[i]);
  }
  uint4 st;
  st.x = (u32)ho[0] | ((u32)ho[1] << 16);
  st.y = (u32)ho[2] | ((u32)ho[3] << 16);
  st.z = (u32)ho[4] | ((u32)ho[5] << 16);
  st.w = (u32)ho[6] | ((u32)ho[7] << 16);
  *(uint4*)(hb + base) = st;
#pragma unroll
  for (int d = 1; d < 64; d <<= 1) { sh += __shfl_xor(sh, d); shh += __shfl_xor(shh, d); }
  if (lane == 0) {
    float m2 = sh * (1.f / FD);
    float v2 = shh * (1.f / FD) - m2 * m2;
    float rs2 = rsqrtf(v2 + 1e-5f);
    scal[nd] = rs2;
    scal[NN + nd] = rs2 * m2;
  }
}

extern "C" void kernel_launch(void* const* d_in, const int* in_sizes, int n_in,
                              void* d_out, int out_size, void* d_ws, size_t ws_size,
                              hipStream_t stream)
{
  const float* feat = (const float*)d_in[0];
  const int* e_src = (const int*)d_in[1];
  const int* e_dst = (const int*)d_in[2];
  const float* Wq  = (const float*)d_in[3];
  const float* Wk  = (const float*)d_in[4];
  const float* Wv  = (const float*)d_in[5];
  const float* Wn  = (const float*)d_in[6];
  const float* Wsk = (const float*)d_in[7];
  const float* Wg  = (const float*)d_in[8];
  const float* l1g = (const float*)d_in[9];
  const float* l1b = (const float*)d_in[10];
  const float* l2g = (const float*)d_in[11];
  const float* l2b = (const float*)d_in[12];
  const float* W1  = (const float*)d_in[13];
  const float* W2  = (const float*)d_in[14];

  char* ws = (char*)d_ws;
  size_t o = 0;
  auto al = [&](size_t b) { char* r = ws + o; o = (o + b + 255) & ~(size_t)255; return r; };

  u16* Af    = (u16*)al((size_t)MP * FD * 2);      // feat fp16
  u16* Bqkvs = (u16*)al((size_t)2048 * FD * 2);    // permuted [q|v interleave, K, SKIP]^T fp16
  u16* Bnt   = (u16*)al((size_t)FD * FD * 2);
  u16* B1t   = (u16*)al((size_t)FD * FD * 2);      // (diag(g2) W1)^T bf16
  u16* B2t   = (u16*)al((size_t)FD * FD * 2);
  float* gA  = (float*)al(FD * 4);
  float* gB  = (float*)al(FD * 4);
  u16* QV    = (u16*)al((size_t)MP * 1024 * 2);    // interleaved [q|v] fp16 per node
  u16* Kb    = (u16*)al((size_t)MP * FD * 2);      // k fp16
  u16* SKIPb = (u16*)al((size_t)MP * FD * 2);      // bf16
  u16* aggb  = (u16*)al((size_t)MP * FD * 2);      // bf16
  u16* hb    = (u16*)al((size_t)MP * FD * 2);      // bf16 (h)
  float* scal= (float*)al((size_t)2 * NN * 4);     // [rs2 | rs2*m2]
  float* uw  = (float*)al(1024 * 4);               // [g2^T W1 | b2^T W1] (zeroed)
  int* deg   = (int*)al((size_t)2 * NN * 4);       // contiguous after uw: one memset
  int* cnt   = deg + NN;
  int* offa  = (int*)al((size_t)(NN + 1) * 4);
  int* esrcs = (int*)al((size_t)NE * 4);
  if (o > ws_size) return;  // ~150 MB needed
  // aliases into dead regions
  u16* rstb = Kb;    // Kb dead after k_edge
  u16* midb = Af;    // Af dead after QKVS GEMM
  float* out = (float*)d_out;

  hipMemsetAsync(uw, 0, 1024 * 4 + (size_t)2 * NN * 4, stream);

  {
    int total = MP * FD / 4 + 2048 * 512 + 3 * 512 * 512 + 512 + 8192 + NE;
    k_wprep<<<dim3((total + 255) / 256), 256, 0, stream>>>(feat, Wq, Wk, Wv, Wsk, Wn, W1, W2, Wg,
        l2g, l2b, e_dst, Af, Bqkvs, Bnt, B1t, B2t, gA, gB, uw, deg);
  }

  // one fp16 GEMM for Q,K,V,SKIP  [MP x 2048 x 512], 128x128 tile, XCD=row%8
  k_gemm<2048, 6, 1><<<dim3(160, 16), 256, 0, stream>>>(Af, Bqkvs, nullptr, QV, Kb, SKIPb, NN);

  k_scan<<<dim3(1), 1024, 0, stream>>>(deg, offa);
  k_scatter<<<dim3((NE + 255) / 256), 256, 0, stream>>>(e_src, e_dst, offa, cnt, esrcs);
  k_edge<<<dim3(MP / 2), 256, 0, stream>>>(offa, esrcs, QV, Kb, aggb);

  k_gemm<512, 2, 0><<<dim3(160, 4), 256, 0, stream>>>(aggb, Bnt, nullptr, rstb, nullptr, nullptr, NN);
  k_gate_ln<<<dim3((NN + 3) / 4), 256, 0, stream>>>(rstb, SKIPb, gA, gB, l1g, l1b, hb, scal);
  k_gemm<512, 8, 0><<<dim3(160, 4), 256, 0, stream>>>(hb, B1t, scal, midb, (u16*)uw, nullptr, NN);
  k_gemm<512, 7, 0><<<dim3(160, 4), 256, 0, stream>>>(midb, B2t, out, nullptr, hb, nullptr, NN);
}

// Round 13
// 310.805 us; speedup vs baseline: 1.0619x; 1.0266x over previous
//
#include <hip/hip_runtime.h>
#include <hip/hip_bf16.h>
#include <hip/hip_fp16.h>

#define NN 20000   // nodes
#define FD 512     // features
#define NH 8       // heads
#define NE 320000  // edges
#define MP 20096   // padded rows = 157*128

typedef unsigned int u32;
typedef unsigned short u16;
typedef __bf16 bf16x8 __attribute__((ext_vector_type(8)));
typedef _Float16 f16x8 __attribute__((ext_vector_type(8)));
typedef float f32x4 __attribute__((ext_vector_type(4)));

#define AS1 __attribute__((address_space(1)))
#define AS3 __attribute__((address_space(3)))

__device__ __forceinline__ u16 f2bf(float f) {
  __hip_bfloat16 h = __float2bfloat16(f);
  union { __hip_bfloat16 b; u16 u; } c; c.b = h; return c.u;
}
__device__ __forceinline__ float bf2f(u32 u) { return __uint_as_float(u << 16); }
__device__ __forceinline__ u16 f2h(float f) {
  union { __half h; u16 u; } c; c.h = __float2half(f); return c.u;
}
__device__ __forceinline__ void gl_lds16(const void* g, void* l) {
  __builtin_amdgcn_global_load_lds((AS1 void*)const_cast<void*>(g), (AS3 void*)l, 16, 0, 0);
}
__device__ __forceinline__ void up_h4(uint2 w, float* f) {
  union { u32 u; __half2 h; } c;
  c.u = w.x; float2 t0 = __half22float2(c.h); f[0]=t0.x; f[1]=t0.y;
  c.u = w.y; float2 t1 = __half22float2(c.h); f[2]=t1.x; f[3]=t1.y;
}
__device__ __forceinline__ void up_b8(uint4 w, float* f) {
  f[0]=bf2f(w.x & 0xffffu); f[1]=bf2f(w.x >> 16);
  f[2]=bf2f(w.y & 0xffffu); f[3]=bf2f(w.y >> 16);
  f[4]=bf2f(w.z & 0xffffu); f[5]=bf2f(w.z >> 16);
  f[6]=bf2f(w.w & 0xffffu); f[7]=bf2f(w.w >> 16);
}

// ---- feat->fp16 + all weight prep + degree histogram in ONE kernel ----
// Bqkvs col n (0..2047), pre-permuted so GEMM MODE6 stores are linear:
//   n<1024: group g=n>>3, j=n&7: j<4 -> Wq dim 4g+(j&3), else Wv dim 4g+(j&3)
//   n<1536: Wk col n-1024 -> Kb ; else Wsk col n-1536 -> SKIPb
__global__ __launch_bounds__(256) void k_wprep(const float* __restrict__ feat,
    const float* __restrict__ Wq, const float* __restrict__ Wk,
    const float* __restrict__ Wv, const float* __restrict__ Wsk,
    const float* __restrict__ Wn, const float* __restrict__ W1,
    const float* __restrict__ W2, const float* __restrict__ Wg,
    const int* __restrict__ e_dst,
    u16* __restrict__ Af, u16* __restrict__ Bqkvs, u16* __restrict__ Bnt,
    u16* __restrict__ B1t, u16* __restrict__ B2t,
    float* __restrict__ gA, float* __restrict__ gB, int* __restrict__ deg)
{
  int idx = blockIdx.x * 256 + threadIdx.x;
  if (idx < MP * FD / 4) {
    size_t i = (size_t)idx * 4;
    float4 v = make_float4(0.f, 0.f, 0.f, 0.f);
    if (i < (size_t)NN * FD) v = *(const float4*)(feat + i);
    *(ushort4*)(Af + i) = make_ushort4(f2h(v.x), f2h(v.y), f2h(v.z), f2h(v.w));
    return;
  }
  idx -= MP * FD / 4;
  if (idx < 2048 * 512) {
    int n = idx >> 9, k = idx & 511;
    float v;
    if (n < 1024) {
      int j = n & 7, dim = (n >> 3) * 4 + (j & 3);
      v = (j < 4) ? Wq[k * 512 + dim] : Wv[k * 512 + dim];
    } else if (n < 1536) v = Wk[k * 512 + (n - 1024)];
    else                 v = Wsk[k * 512 + (n - 1536)];
    Bqkvs[idx] = f2h(v);
    return;
  }
  idx -= 2048 * 512;
  if (idx < 512 * 512) { int n = idx >> 9, k = idx & 511; Bnt[idx] = f2bf(Wn[k * 512 + n]); return; }
  idx -= 512 * 512;
  if (idx < 512 * 512) { int n = idx >> 9, k = idx & 511; B1t[idx] = f2bf(W1[k * 512 + n]); return; }
  idx -= 512 * 512;
  if (idx < 512 * 512) { int n = idx >> 9, k = idx & 511; B2t[idx] = f2bf(W2[k * 512 + n]); return; }
  idx -= 512 * 512;
  if (idx < 512) {
    gA[idx] = Wg[idx] + Wg[2 * 512 + idx];
    gB[idx] = Wg[512 + idx] - Wg[2 * 512 + idx];
    return;
  }
  idx -= 512;
  if (idx < NE) atomicAdd(&deg[e_dst[idx]], 1);
}

// ---- GEMM: A[M,512] x Bt[NCOLS,512] (both u16-encoded, FP16 or bf16) ----
// 128x128 tile, BK=32 double-buffer at 32 KB LDS, 4 blocks/CU, XCD=row%8.
// MODE: 1=relu+bf16->Cb, 2=bf16->Cb,
//       6=QKVS split store: col<1024 -> Cb=QV (interleaved q|v fp16, linear);
//                           col<1536 -> Cb2=Kb fp16; else Cb3=SKIPb bf16
//       7=h+ffn: Cf[o] = bf2f(Cb2[o]) + v   (writes d_out once)
template<int NCOLS, int MODE, int FP16>
__global__ __launch_bounds__(256, 4) void k_gemm(
    const u16* __restrict__ A, const u16* __restrict__ B,
    float* __restrict__ Cf, u16* __restrict__ Cb, u16* __restrict__ Cb2,
    u16* __restrict__ Cb3, int Mreal)
{
  const long brow = (long)blockIdx.x * 128;
  if (brow >= MP) return;
  __shared__ u16 sA[2][128 * 32];
  __shared__ u16 sB[2][128 * 32];
  const int tid = threadIdx.x, lane = tid & 63, w = tid >> 6;
  const int wr = w >> 1, wc = w & 1;
  const long bcol = (long)blockIdx.y * 128;
  const int srl = tid >> 2, scl = (tid & 3) * 8;

  auto stage = [&](int b, int kt) {
#pragma unroll
    for (int s = 0; s < 2; s++) {
      gl_lds16(A + (brow + s * 64 + srl) * FD + kt + scl, &sA[b][s * 2048 + w * 512]);
      gl_lds16(B + (bcol + s * 64 + srl) * FD + kt + scl, &sB[b][s * 2048 + w * 512]);
    }
  };

  f32x4 acc[4][4] = {};
  stage(0, 0);
  __syncthreads();
  int cur = 0;
  const int ro = (lane >> 4) * 8;
  for (int kt = 0; kt < FD; kt += 32) {
    if (kt + 32 < FD) stage(cur ^ 1, kt + 32);
#pragma unroll
    for (int m = 0; m < 4; m++) {
      const u16* pa = &sA[cur][(wr * 64 + m * 16 + (lane & 15)) * 32 + ro];
#pragma unroll
      for (int n = 0; n < 4; n++) {
        const u16* pb = &sB[cur][(wc * 64 + n * 16 + (lane & 15)) * 32 + ro];
        if constexpr (FP16)
          acc[m][n] = __builtin_amdgcn_mfma_f32_16x16x32_f16(
              *(const f16x8*)pa, *(const f16x8*)pb, acc[m][n], 0, 0, 0);
        else
          acc[m][n] = __builtin_amdgcn_mfma_f32_16x16x32_bf16(
              *(const bf16x8*)pa, *(const bf16x8*)pb, acc[m][n], 0, 0, 0);
      }
    }
    __syncthreads();
    cur ^= 1;
  }
#pragma unroll
  for (int m = 0; m < 4; m++) {
    long row0 = brow + wr * 64 + m * 16 + (lane >> 4) * 4;
#pragma unroll
    for (int n = 0; n < 4; n++) {
      long col = bcol + wc * 64 + n * 16 + (lane & 15);
#pragma unroll
      for (int j = 0; j < 4; j++) {
        long row = row0 + j;
        if (row < Mreal) {
          float v = acc[m][n][j];
          if constexpr (MODE == 1) Cb[row * NCOLS + col] = f2bf(fmaxf(v, 0.f));
          else if constexpr (MODE == 2) Cb[row * NCOLS + col] = f2bf(v);
          else if constexpr (MODE == 6) {
            if (col < 1024)      Cb[row * 1024 + col] = f2h(v);
            else if (col < 1536) Cb2[row * 512 + (col - 1024)] = f2h(v);
            else                 Cb3[row * 512 + (col - 1536)] = f2bf(v);
          } else {  // MODE 7
            long o = row * NCOLS + col;
            Cf[o] = bf2f((u32)Cb2[o]) + v;
          }
        }
      }
    }
  }
}

// ---- single-pass scan: thread t serially scans 20 elems, 2 block barriers ----
__global__ __launch_bounds__(1024) void k_scan(const int* __restrict__ deg, int* __restrict__ offa)
{
  __shared__ int wsum[16];
  const int tid = threadIdx.x, lane = tid & 63, wid = tid >> 6;
  const int base = tid * 20;
  int loc[20];
  int s = 0;
#pragma unroll
  for (int j = 0; j < 20; j++) {
    int i = base + j;
    int v = (i < NN) ? deg[i] : 0;
    s += v; loc[j] = s;
  }
  int incl = s;
#pragma unroll
  for (int d = 1; d < 64; d <<= 1) { int t = __shfl_up(incl, d); if (lane >= d) incl += t; }
  if (lane == 63) wsum[wid] = incl;
  __syncthreads();
  if (tid < 16) {
    int ws = wsum[tid];
#pragma unroll
    for (int d = 1; d < 16; d <<= 1) { int t = __shfl_up(ws, d, 16); if (tid >= d) ws += t; }
    wsum[tid] = ws;
  }
  __syncthreads();
  int prev = incl - s + (wid ? wsum[wid - 1] : 0);
  if (tid == 0) offa[0] = 0;
#pragma unroll
  for (int j = 0; j < 20; j++) {
    int i = base + j;
    if (i < NN) offa[i + 1] = prev + loc[j];
  }
}

__global__ __launch_bounds__(256) void k_scatter(const int* __restrict__ src, const int* __restrict__ dst,
    const int* __restrict__ offa, int* __restrict__ cnt, int* __restrict__ esrcs)
{
  int e = blockIdx.x * 256 + threadIdx.x;
  if (e >= NE) return;
  int d = dst[e];
  int p = offa[d] + atomicAdd(&cnt[d], 1);
  esrcs[p] = src[e];
}

// ---- fused edge pass: 2 waves per dst node, interleaved QV (one uint4/lane/edge) ----
__global__ __launch_bounds__(256) void k_edge(const int* __restrict__ offa,
    const int* __restrict__ esrcs, const u16* __restrict__ QV,
    const u16* __restrict__ Kb, u16* __restrict__ aggb)
{
  int wid = blockIdx.x * 4 + (threadIdx.x >> 6);
  int nd = wid >> 1, half = wid & 1;
  int lane = threadIdx.x & 63;
  if (nd >= MP) return;
  const int g = half * 64 + lane;          // 4-dim group index, dims [4g,4g+4)
  u16* op = aggb + (size_t)nd * FD + g * 4;
  if (nd >= NN) { *(ushort4*)op = make_ushort4(0, 0, 0, 0); return; }
  uint2 kw = *(const uint2*)(Kb + (size_t)nd * 512 + g * 4);
  float kx[4]; up_h4(kw, kx);
  int b0 = offa[nd], b1 = offa[nd + 1];
  float den = 0.f, a0 = 0.f, a1 = 0.f, a2 = 0.f, a3 = 0.f;
  for (int p = b0; p < b1; p += 8) {
    int ss[8]; uint4 qv[8];
#pragma unroll
    for (int u = 0; u < 8; u++) { int ix = p + u; ss[u] = esrcs[ix < b1 ? ix : b1 - 1]; }
#pragma unroll
    for (int u = 0; u < 8; u++)
      qv[u] = *(const uint4*)(QV + (size_t)ss[u] * 1024 + g * 8);
#pragma unroll
    for (int u = 0; u < 8; u++) {
      float qx[4]; up_h4(make_uint2(qv[u].x, qv[u].y), qx);
      float d = qx[0]*kx[0] + qx[1]*kx[1] + qx[2]*kx[2] + qx[3]*kx[3];
      d += __shfl_xor(d, 1); d += __shfl_xor(d, 2);
      d += __shfl_xor(d, 4); d += __shfl_xor(d, 8);
      float ex = __expf(fminf(fmaxf(d, -5.f), 5.f) * 8.f - 40.f);
      ex = (p + u < b1) ? ex : 0.f;
      den += ex;
      float vx[4]; up_h4(make_uint2(qv[u].z, qv[u].w), vx);
      a0 += ex * vx[0]; a1 += ex * vx[1]; a2 += ex * vx[2]; a3 += ex * vx[3];
    }
  }
  float rd = 1.f / den;
  *(ushort4*)op = make_ushort4(f2bf(a0*rd), f2bf(a1*rd), f2bf(a2*rd), f2bf(a3*rd));
}

// ---- gate GEMV + gated residual + LN1 (-> h bf16) + LN2 (-> h2b bf16) ----
// one wave per row: 64 lanes x 8 elems, shfl-only reductions, zero barriers.
__global__ __launch_bounds__(256) void k_gate_ln(const u16* __restrict__ rstb,
    const u16* __restrict__ skpb, const float* __restrict__ gA, const float* __restrict__ gB,
    const float* __restrict__ g1, const float* __restrict__ b1,
    const float* __restrict__ g2, const float* __restrict__ b2,
    u16* __restrict__ hb, u16* __restrict__ h2b)
{
  int nd = blockIdx.x * 4 + (threadIdx.x >> 6);
  int lane = threadIdx.x & 63;
  if (nd >= NN) return;
  const size_t base = (size_t)nd * FD + lane * 8;
  float r[8], s[8], a[8], b[8];
  up_b8(*(const uint4*)(rstb + base), r);
  up_b8(*(const uint4*)(skpb + base), s);
  *(float4*)&a[0] = *(const float4*)(gA + lane * 8);
  *(float4*)&a[4] = *(const float4*)(gA + lane * 8 + 4);
  *(float4*)&b[0] = *(const float4*)(gB + lane * 8);
  *(float4*)&b[4] = *(const float4*)(gB + lane * 8 + 4);
  float gd = 0.f;
#pragma unroll
  for (int i = 0; i < 8; i++) gd += r[i] * a[i] + s[i] * b[i];
#pragma unroll
  for (int d = 1; d < 64; d <<= 1) gd += __shfl_xor(gd, d);
  float g = 1.f / (1.f + __expf(-gd));
  float x[8], sx = 0.f, sxx = 0.f;
#pragma unroll
  for (int i = 0; i < 8; i++) {
    x[i] = g * r[i] + (1.f - g) * s[i];
    sx += x[i]; sxx += x[i] * x[i];
  }
#pragma unroll
  for (int d = 1; d < 64; d <<= 1) { sx += __shfl_xor(sx, d); sxx += __shfl_xor(sxx, d); }
  float m1 = sx * (1.f / FD);
  float v1 = sxx * (1.f / FD) - m1 * m1;
  float rs = rsqrtf(v1 + 1e-5f);
  float G1[8], Bb1[8];
  *(float4*)&G1[0] = *(const float4*)(g1 + lane * 8);
  *(float4*)&G1[4] = *(const float4*)(g1 + lane * 8 + 4);
  *(float4*)&Bb1[0] = *(const float4*)(b1 + lane * 8);
  *(float4*)&Bb1[4] = *(const float4*)(b1 + lane * 8 + 4);
  float h[8], sh = 0.f, shh = 0.f;
  u16 ho[8];
#pragma unroll
  for (int i = 0; i < 8; i++) {
    h[i] = (x[i] - m1) * rs * G1[i] + Bb1[i];
    sh += h[i]; shh += h[i] * h[i];
    ho[i] = f2bf(h[i]);
  }
  uint4 st;
  st.x = (u32)ho[0] | ((u32)ho[1] << 16);
  st.y = (u32)ho[2] | ((u32)ho[3] << 16);
  st.z = (u32)ho[4] | ((u32)ho[5] << 16);
  st.w = (u32)ho[6] | ((u32)ho[7] << 16);
  *(uint4*)(hb + base) = st;
#pragma unroll
  for (int d = 1; d < 64; d <<= 1) { sh += __shfl_xor(sh, d); shh += __shfl_xor(shh, d); }
  float m2 = sh * (1.f / FD);
  float v2 = shh * (1.f / FD) - m2 * m2;
  float rs2 = rsqrtf(v2 + 1e-5f);
  float G2[8], Bb2[8];
  *(float4*)&G2[0] = *(const float4*)(g2 + lane * 8);
  *(float4*)&G2[4] = *(const float4*)(g2 + lane * 8 + 4);
  *(float4*)&Bb2[0] = *(const float4*)(b2 + lane * 8);
  *(float4*)&Bb2[4] = *(const float4*)(b2 + lane * 8 + 4);
  u16 h2o[8];
#pragma unroll
  for (int i = 0; i < 8; i++)
    h2o[i] = f2bf((h[i] - m2) * rs2 * G2[i] + Bb2[i]);
  uint4 st2;
  st2.x = (u32)h2o[0] | ((u32)h2o[1] << 16);
  st2.y = (u32)h2o[2] | ((u32)h2o[3] << 16);
  st2.z = (u32)h2o[4] | ((u32)h2o[5] << 16);
  st2.w = (u32)h2o[6] | ((u32)h2o[7] << 16);
  *(uint4*)(h2b + base) = st2;
}

extern "C" void kernel_launch(void* const* d_in, const int* in_sizes, int n_in,
                              void* d_out, int out_size, void* d_ws, size_t ws_size,
                              hipStream_t stream)
{
  const float* feat = (const float*)d_in[0];
  const int* e_src = (const int*)d_in[1];
  const int* e_dst = (const int*)d_in[2];
  const float* Wq  = (const float*)d_in[3];
  const float* Wk  = (const float*)d_in[4];
  const float* Wv  = (const float*)d_in[5];
  const float* Wn  = (const float*)d_in[6];
  const float* Wsk = (const float*)d_in[7];
  const float* Wg  = (const float*)d_in[8];
  const float* l1g = (const float*)d_in[9];
  const float* l1b = (const float*)d_in[10];
  const float* l2g = (const float*)d_in[11];
  const float* l2b = (const float*)d_in[12];
  const float* W1  = (const float*)d_in[13];
  const float* W2  = (const float*)d_in[14];

  char* ws = (char*)d_ws;
  size_t o = 0;
  auto al = [&](size_t b) { char* r = ws + o; o = (o + b + 255) & ~(size_t)255; return r; };

  u16* Af    = (u16*)al((size_t)MP * FD * 2);      // feat fp16
  u16* Bqkvs = (u16*)al((size_t)2048 * FD * 2);    // permuted [q|v interleave, K, SKIP]^T fp16
  u16* Bnt   = (u16*)al((size_t)FD * FD * 2);
  u16* B1t   = (u16*)al((size_t)FD * FD * 2);
  u16* B2t   = (u16*)al((size_t)FD * FD * 2);
  float* gA  = (float*)al(FD * 4);
  float* gB  = (float*)al(FD * 4);
  u16* QV    = (u16*)al((size_t)MP * 1024 * 2);    // interleaved [q|v] fp16 per node
  u16* Kb    = (u16*)al((size_t)MP * FD * 2);      // k fp16
  u16* SKIPb = (u16*)al((size_t)MP * FD * 2);      // bf16
  u16* aggb  = (u16*)al((size_t)MP * FD * 2);      // bf16
  u16* hb    = (u16*)al((size_t)MP * FD * 2);      // bf16 (h)
  u16* h2b   = (u16*)al((size_t)MP * FD * 2);      // bf16 (LN2 out)
  int* deg   = (int*)al((size_t)2 * NN * 4);
  int* cnt   = deg + NN;
  int* offa  = (int*)al((size_t)(NN + 1) * 4);
  int* esrcs = (int*)al((size_t)NE * 4);
  if (o > ws_size) return;  // ~170 MB needed
  // aliases into dead regions
  u16* rstb = Kb;    // Kb dead after k_edge
  u16* midb = Af;    // Af dead after QKVS GEMM
  float* out = (float*)d_out;

  hipMemsetAsync(deg, 0, (size_t)2 * NN * 4, stream);

  {
    int total = MP * FD / 4 + 2048 * 512 + 3 * 512 * 512 + 512 + NE;
    k_wprep<<<dim3((total + 255) / 256), 256, 0, stream>>>(feat, Wq, Wk, Wv, Wsk, Wn, W1, W2, Wg,
        e_dst, Af, Bqkvs, Bnt, B1t, B2t, gA, gB, deg);
  }

  // one fp16 GEMM for Q,K,V,SKIP  [MP x 2048 x 512], 128x128 tile, XCD=row%8
  k_gemm<2048, 6, 1><<<dim3(160, 16), 256, 0, stream>>>(Af, Bqkvs, nullptr, QV, Kb, SKIPb, NN);

  k_scan<<<dim3(1), 1024, 0, stream>>>(deg, offa);
  k_scatter<<<dim3((NE + 255) / 256), 256, 0, stream>>>(e_src, e_dst, offa, cnt, esrcs);
  k_edge<<<dim3(MP / 2), 256, 0, stream>>>(offa, esrcs, QV, Kb, aggb);

  k_gemm<512, 2, 0><<<dim3(160, 4), 256, 0, stream>>>(aggb, Bnt, nullptr, rstb, nullptr, nullptr, NN);
  k_gate_ln<<<dim3((NN + 3) / 4), 256, 0, stream>>>(rstb, SKIPb, gA, gB, l1g, l1b, l2g, l2b, hb, h2b);
  k_gemm<512, 1, 0><<<dim3(160, 4), 256, 0, stream>>>(h2b, B1t, nullptr, midb, nullptr, nullptr, NN);
  k_gemm<512, 7, 0><<<dim3(160, 4), 256, 0, stream>>>(midb, B2t, out, nullptr, hb, nullptr, NN);
}